// Round 4
// baseline (276.403 us; speedup 1.0000x reference)
//
#include <hip/hip_runtime.h>
#include <math.h>

// MHSA_27582279975470 — bf16/fp16 MFMA pipeline for MI355X (gfx950)
// B=4, C=256, NH=8, HD=32, H=W=64 -> Nq=4096, SR=2 -> Mkv=1024
//
// R4: (a) attn 16 q/wave -> 2048 blocks (8/CU, 32 waves/CU nominal; R3 was
// wave-starved at 4 blocks/CU, 45% pipe busy). Softmax shift folded into
// QK MFMA C-operand. (b) k_im2col/P_t deleted: gemm_kv gathers P-rows
// directly from xT (32-wide K-chunks never cross tap boundaries).

typedef __bf16 bf16;
typedef __attribute__((ext_vector_type(8))) __bf16 bf16x8;
typedef __attribute__((ext_vector_type(4))) float f32x4;
typedef __attribute__((ext_vector_type(4))) _Float16 f16x4;

#define MFMA16 __builtin_amdgcn_mfma_f32_16x16x32_bf16      // D[row=A-row][col=B-row]
#define MFMA16H __builtin_amdgcn_mfma_f32_16x16x16f16       // k=16, fp16 in

#define QSCALE 0.25503486f   // (1/sqrt(32)) * log2(e)
#define SOFTMAX_SHIFT 10.0f  // constant exp2-domain shift (softmax-invariant)

// ---------------------------------------------------------------- prep weights
__global__ void k_prep_w(const float* __restrict__ Wq, const float* __restrict__ Wk,
                         const float* __restrict__ Wv,
                         bf16* __restrict__ Wq_bf, bf16* __restrict__ Wkv_bf) {
    int idx = blockIdx.x * 256 + threadIdx.x;          // 0..65535
    Wq_bf[idx] = (bf16)(Wq[idx] * QSCALE);             // fold scale*log2e into q
#pragma unroll
    for (int r = 0; r < 8; r++) {
        int e = idx + r * 65536;                       // 0..524287
        int c = e >> 10, kk = e & 1023;                // c: 0..511 (k then v)
        int tap = kk >> 8, i = kk & 255;               // K-order: tap*256 + i
        const float* Wsrc = (c < 256) ? Wk : Wv;
        int cs = c & 255;
        // W[o][i][dy][dx] flat: o*1024 + i*4 + tap (tap = dy*2+dx)
        Wkv_bf[e] = (bf16)Wsrc[(cs * 256 + i) * 4 + tap];
    }
}

// ---------------------------------------------------------------- x transpose
__global__ void k_xT(const float* __restrict__ x, bf16* __restrict__ xT) {
    // grid (64 n-tiles, 4 c-tiles, 4 b), 256 thr, 64x64 tile
    int b = blockIdx.z, c0 = blockIdx.y * 64, n0 = blockIdx.x * 64;
    __shared__ float tile[64][65];
    int t = threadIdx.x;
    const float* xp = x + (size_t)(b * 256 + c0) * 4096 + n0;
#pragma unroll
    for (int k2 = 0; k2 < 16; k2++) {
        int flat = k2 * 256 + t;
        int row = flat >> 6, col = flat & 63;          // row = c-local, col = n-local
        tile[row][col] = xp[(size_t)row * 4096 + col];
    }
    __syncthreads();
    bf16* op = xT + (size_t)(b * 4096 + n0) * 256 + c0;
#pragma unroll
    for (int k2 = 0; k2 < 16; k2++) {
        int flat = k2 * 256 + t;
        int row = flat >> 6, col = flat & 63;          // row = n-local, col = c-local
        op[(size_t)row * 256 + col] = (bf16)tile[col][row];
    }
}

// ---------------------------------------------------------------- q GEMM
// D[n][c] = sum_i xT[n][i] * Wq_bf[c][i]   (A rows = xT, B rows = Wq_bf)
__launch_bounds__(256)
__global__ void k_gemm_q(const bf16* __restrict__ xT, const bf16* __restrict__ Wq_bf,
                         bf16* __restrict__ q_t) {
    int b = blockIdx.z;
    int n0 = blockIdx.x * 64, c0 = blockIdx.y * 64;
    int t = threadIdx.x, l = t & 63, w = t >> 6;
    int wn = (w & 1) * 32, wc = (w >> 1) * 32;         // wave tile 32x32 in 64x64 block
    int lr = l & 15, lg = l >> 4;
    const bf16* Ab = xT + (size_t)(b * 4096 + n0 + wn + lr) * 256 + lg * 8;
    const bf16* Bb = Wq_bf + (size_t)(c0 + wc + lr) * 256 + lg * 8;
    f32x4 acc[2][2] = {};
#pragma unroll
    for (int kk = 0; kk < 8; kk++) {
        bf16x8 a0 = *(const bf16x8*)(Ab + kk * 32);
        bf16x8 a1 = *(const bf16x8*)(Ab + 16 * 256 + kk * 32);
        bf16x8 b0 = *(const bf16x8*)(Bb + kk * 32);
        bf16x8 b1 = *(const bf16x8*)(Bb + 16 * 256 + kk * 32);
        acc[0][0] = MFMA16(a0, b0, acc[0][0], 0, 0, 0);
        acc[0][1] = MFMA16(a0, b1, acc[0][1], 0, 0, 0);
        acc[1][0] = MFMA16(a1, b0, acc[1][0], 0, 0, 0);
        acc[1][1] = MFMA16(a1, b1, acc[1][1], 0, 0, 0);
    }
#pragma unroll
    for (int i = 0; i < 2; i++)
#pragma unroll
        for (int j = 0; j < 2; j++) {
            int cc = c0 + wc + j * 16 + lr;            // D col = lane&15
            int h = cc >> 5, d = cc & 31;
#pragma unroll
            for (int r = 0; r < 4; r++) {
                int n = n0 + wn + i * 16 + lg * 4 + r; // D row = (lane>>4)*4+r
                q_t[((size_t)(b * 8 + h) * 4096 + n) * 32 + d] = (bf16)acc[i][j][r];
            }
        }
}

// ---------------------------------------------------------------- kv conv GEMM
// P-row fragments gathered directly from xT: P[m][k], k = tap*256+i maps to
// xT[n(m,tap)][i]; a 32-wide kk chunk stays within one tap.
__device__ inline void p_row_ptrs(const bf16* __restrict__ xb, int m, int lgofs,
                                  const bf16* __restrict__ p[4]) {
    int y = m >> 5, xw = m & 31;
    int nb = y * 128 + xw * 2;                         // top-left pixel of 2x2 patch
#pragma unroll
    for (int tap = 0; tap < 4; tap++) {
        int n = nb + (tap >> 1) * 64 + (tap & 1);
        p[tap] = xb + (size_t)n * 256 + lgofs;
    }
}
__device__ inline void c_row_ptrs(const bf16* __restrict__ row, int lgofs,
                                  const bf16* __restrict__ p[4]) {
#pragma unroll
    for (int tap = 0; tap < 4; tap++) p[tap] = row + tap * 256 + lgofs;
}

// zz<4 : kpos  D[m][c]  (A rows = P(xT),  B rows = Wkv_bf[0..255])   + rel bias
// zz>=4: v     D[c][m]  (A rows = Wkv_bf[256..511], B rows = P(xT)) -> fp16
__launch_bounds__(256)
__global__ void k_gemm_kv(const bf16* __restrict__ xT, const bf16* __restrict__ Wkv_bf,
                          const float* __restrict__ rel_h, const float* __restrict__ rel_w,
                          bf16* __restrict__ kpos_t, _Float16* __restrict__ v_td) {
    int b = blockIdx.z;
    int m0 = blockIdx.x * 64;
    int zz = blockIdx.y;
    bool vmode = zz >= 4;
    int c0 = (zz & 3) * 64;
    int t = threadIdx.x, l = t & 63, w = t >> 6;
    int wr = (w & 1) * 32, wc = (w >> 1) * 32;
    int lr = l & 15, lg = l >> 4;
    int lgofs = lg * 8;
    const bf16* xb = xT + (size_t)b * 4096 * 256;
    const bf16 *A0[4], *A1[4], *B0[4], *B1[4];
    if (!vmode) {
        p_row_ptrs(xb, m0 + wr + lr, lgofs, A0);
        p_row_ptrs(xb, m0 + wr + 16 + lr, lgofs, A1);
        c_row_ptrs(Wkv_bf + (size_t)(c0 + wc + lr) * 1024, lgofs, B0);
        c_row_ptrs(Wkv_bf + (size_t)(c0 + wc + 16 + lr) * 1024, lgofs, B1);
    } else {
        c_row_ptrs(Wkv_bf + (size_t)(256 + c0 + wr + lr) * 1024, lgofs, A0);
        c_row_ptrs(Wkv_bf + (size_t)(256 + c0 + wr + 16 + lr) * 1024, lgofs, A1);
        p_row_ptrs(xb, m0 + wc + lr, lgofs, B0);
        p_row_ptrs(xb, m0 + wc + 16 + lr, lgofs, B1);
    }
    f32x4 acc[2][2] = {};
#pragma unroll
    for (int tap = 0; tap < 4; tap++) {
#pragma unroll
        for (int j = 0; j < 8; j++) {
            int o = j * 32;
            bf16x8 a0 = *(const bf16x8*)(A0[tap] + o);
            bf16x8 a1 = *(const bf16x8*)(A1[tap] + o);
            bf16x8 b0 = *(const bf16x8*)(B0[tap] + o);
            bf16x8 b1 = *(const bf16x8*)(B1[tap] + o);
            acc[0][0] = MFMA16(a0, b0, acc[0][0], 0, 0, 0);
            acc[0][1] = MFMA16(a0, b1, acc[0][1], 0, 0, 0);
            acc[1][0] = MFMA16(a1, b0, acc[1][0], 0, 0, 0);
            acc[1][1] = MFMA16(a1, b1, acc[1][1], 0, 0, 0);
        }
    }
    if (!vmode) {
#pragma unroll
        for (int i = 0; i < 2; i++)
#pragma unroll
            for (int j = 0; j < 2; j++) {
                int cc = c0 + wc + j * 16 + lr;
#pragma unroll
                for (int r = 0; r < 4; r++) {
                    int m = m0 + wr + i * 16 + lg * 4 + r;
                    // pos[h,d,m] = rel_w[h,d,y=m>>5] + rel_h[h,d,x=m&31]
                    float val = acc[i][j][r] + rel_w[cc * 32 + (m >> 5)]
                                            + rel_h[cc * 32 + (m & 31)];
                    kpos_t[((size_t)(b * 8 + (cc >> 5)) * 1024 + m) * 32 + (cc & 31)] = (bf16)val;
                }
            }
    } else {
#pragma unroll
        for (int i = 0; i < 2; i++)
#pragma unroll
            for (int j = 0; j < 2; j++) {
                int m = m0 + wc + j * 16 + lr;
#pragma unroll
                for (int r = 0; r < 4; r++) {
                    int cc = c0 + wr + i * 16 + lg * 4 + r;
                    v_td[((size_t)(b * 8 + (cc >> 5)) * 32 + (cc & 31)) * 1024 + m] = (_Float16)acc[i][j][r];
                }
            }
    }
}

// ---------------------------------------------------------------- attention
// One wave = 16 queries. S^T = K·Q^T (operand swap) lands P in the exact
// 16x16x16 A-frag layout (col n = lane&15, rows m = (lane>>4)*4+r).
// Softmax shift pre-loaded via MFMA C operand. No LDS, no cross-lane in loop.
__launch_bounds__(256)
__global__ void k_attn(const bf16* __restrict__ q_t, const bf16* __restrict__ kpos_t,
                       const _Float16* __restrict__ v_td, float* __restrict__ out) {
    int b = blockIdx.z, h = blockIdx.y;
    int w = threadIdx.x >> 6, l = threadIdx.x & 63;
    int n0 = blockIdx.x * 64 + w * 16;
    int lr = l & 15, lg = l >> 4;
    const size_t bh = (size_t)(b * 8 + h);
    // Q as B-operand: B row j = n = lr, k = d = lg*8..+8
    bf16x8 bq = *(const bf16x8*)(q_t + (bh * 4096 + n0 + lr) * 32 + lg * 8);
    const bf16* Kb = kpos_t + bh * 1024 * 32;
    const _Float16* Vb = v_td + bh * 32 * 1024;
    f32x4 accO[2] = {};             // [d-tile]: col d = lr, row n = lg*4+r
    float ps = 0.f;                 // per-lane row-sum partial (n = lr)
    const f32x4 zs = {-SOFTMAX_SHIFT, -SOFTMAX_SHIFT, -SOFTMAX_SHIFT, -SOFTMAX_SHIFT};
#pragma unroll 4
    for (int t = 0; t < 64; t++) {
        // K as A-operand: A row i = m = lr, k = d
        bf16x8 ak = *(const bf16x8*)(Kb + (size_t)(t * 16 + lr) * 32 + lg * 8);
        f32x4 s = MFMA16(ak, bq, zs, 0, 0, 0);    // lane: col n=lr, row m=t*16+lg*4+r
        f16x4 p;
#pragma unroll
        for (int r = 0; r < 4; r++) {
            float e = fminf(__builtin_amdgcn_exp2f(s[r]), 65504.f);
            ps += e;
            p[r] = (_Float16)e;
        }
        // V as B-operand (k=16): B row j = d = lr, k = m = lg*4+jj
        f16x4 v0 = *(const f16x4*)(Vb + (size_t)lr * 1024 + t * 16 + lg * 4);
        f16x4 v1 = *(const f16x4*)(Vb + (size_t)(16 + lr) * 1024 + t * 16 + lg * 4);
        accO[0] = MFMA16H(p, v0, accO[0], 0, 0, 0);
        accO[1] = MFMA16H(p, v1, accO[1], 0, 0, 0);
    }
    // row sums: lanes {lr, lr+16, lr+32, lr+48} hold disjoint m-partials
    ps += __shfl_xor(ps, 16, 64);
    ps += __shfl_xor(ps, 32, 64);
    float inv[4];
#pragma unroll
    for (int r = 0; r < 4; r++) inv[r] = 1.0f / __shfl(ps, lg * 4 + r, 64);
#pragma unroll
    for (int dt = 0; dt < 2; dt++) {
        int c = h * 32 + dt * 16 + lr;     // accO col = d = lr
        float* op = out + (size_t)(b * 256 + c) * 4096 + n0 + lg * 4;
        f32x4 o;
#pragma unroll
        for (int r = 0; r < 4; r++) o[r] = accO[dt][r] * inv[r];
        *(f32x4*)op = o;
    }
}

// ---------------------------------------------------------------- launcher
extern "C" void kernel_launch(void* const* d_in, const int* in_sizes, int n_in,
                              void* d_out, int out_size, void* d_ws, size_t ws_size,
                              hipStream_t stream) {
    const float* x    = (const float*)d_in[0];
    const float* Wq   = (const float*)d_in[1];
    const float* Wk   = (const float*)d_in[2];
    const float* Wv   = (const float*)d_in[3];
    const float* relh = (const float*)d_in[4];
    const float* relw = (const float*)d_in[5];
    float* out = (float*)d_out;
    char* ws = (char*)d_ws;

    bf16*      xT     = (bf16*)(ws);                                  // 8 MiB
    bf16*      q_t    = (bf16*)(ws + (8u << 20));                     // 8 MiB
    bf16*      kposT  = (bf16*)(ws + (16u << 20));                    // 2 MiB
    _Float16*  v_td   = (_Float16*)(ws + (18u << 20));                // 2 MiB
    bf16*      Wq_bf  = (bf16*)(ws + (20u << 20));                    // 128 KiB
    bf16*      Wkv_bf = (bf16*)(ws + (20u << 20) + (256u << 10));     // 1 MiB

    k_prep_w <<<256,            256, 0, stream>>>(Wq, Wk, Wv, Wq_bf, Wkv_bf);
    k_xT     <<<dim3(64, 4, 4), 256, 0, stream>>>(x, xT);
    k_gemm_q <<<dim3(64, 4, 4), 256, 0, stream>>>(xT, Wq_bf, q_t);
    k_gemm_kv<<<dim3(16, 8, 4), 256, 0, stream>>>(xT, Wkv_bf, relh, relw, kposT, v_td);
    k_attn   <<<dim3(64, 8, 4), 256, 0, stream>>>(q_t, kposT, v_td, out);
}

// Round 5
// 169.964 us; speedup vs baseline: 1.6262x; 1.6262x over previous
//
#include <hip/hip_runtime.h>
#include <math.h>

// MHSA_27582279975470 — bf16/fp16 MFMA pipeline for MI355X (gfx950)
// B=4, C=256, NH=8, HD=32, H=W=64 -> Nq=4096, SR=2 -> Mkv=1024
//
// R5: attn rewritten as shared-K/V LDS-staged block. R4 post-mortem: attn is
// bound by redundant K/V fragment traffic (each wave streamed 128KB K+V from
// L2), not wave count. Now 4 waves x 32q = 128 queries/block share K/V staged
// in LDS (4 passes x 256 m, 33KB). Global K/V traffic 1GB -> 128MB; inner
// loop fed by ds_read instead of 200-cyc L2 loads. Producers unchanged.

typedef __bf16 bf16;
typedef __attribute__((ext_vector_type(8))) __bf16 bf16x8;
typedef __attribute__((ext_vector_type(4))) float f32x4;
typedef __attribute__((ext_vector_type(4))) _Float16 f16x4;

#define MFMA16 __builtin_amdgcn_mfma_f32_16x16x32_bf16      // D[row=A-row][col=B-row]
#define MFMA16H __builtin_amdgcn_mfma_f32_16x16x16f16       // k=16, fp16 in

#define QSCALE 0.25503486f   // (1/sqrt(32)) * log2(e)
#define SOFTMAX_SHIFT 10.0f  // constant exp2-domain shift (softmax-invariant)

// ---------------------------------------------------------------- prep weights
__global__ void k_prep_w(const float* __restrict__ Wq, const float* __restrict__ Wk,
                         const float* __restrict__ Wv,
                         bf16* __restrict__ Wq_bf, bf16* __restrict__ Wkv_bf) {
    int idx = blockIdx.x * 256 + threadIdx.x;          // 0..65535
    Wq_bf[idx] = (bf16)(Wq[idx] * QSCALE);             // fold scale*log2e into q
#pragma unroll
    for (int r = 0; r < 8; r++) {
        int e = idx + r * 65536;                       // 0..524287
        int c = e >> 10, kk = e & 1023;                // c: 0..511 (k then v)
        int tap = kk >> 8, i = kk & 255;               // K-order: tap*256 + i
        const float* Wsrc = (c < 256) ? Wk : Wv;
        int cs = c & 255;
        // W[o][i][dy][dx] flat: o*1024 + i*4 + tap (tap = dy*2+dx)
        Wkv_bf[e] = (bf16)Wsrc[(cs * 256 + i) * 4 + tap];
    }
}

// ---------------------------------------------------------------- x transpose
__global__ void k_xT(const float* __restrict__ x, bf16* __restrict__ xT) {
    // grid (64 n-tiles, 4 c-tiles, 4 b), 256 thr, 64x64 tile
    int b = blockIdx.z, c0 = blockIdx.y * 64, n0 = blockIdx.x * 64;
    __shared__ float tile[64][65];
    int t = threadIdx.x;
    const float* xp = x + (size_t)(b * 256 + c0) * 4096 + n0;
#pragma unroll
    for (int k2 = 0; k2 < 16; k2++) {
        int flat = k2 * 256 + t;
        int row = flat >> 6, col = flat & 63;          // row = c-local, col = n-local
        tile[row][col] = xp[(size_t)row * 4096 + col];
    }
    __syncthreads();
    bf16* op = xT + (size_t)(b * 4096 + n0) * 256 + c0;
#pragma unroll
    for (int k2 = 0; k2 < 16; k2++) {
        int flat = k2 * 256 + t;
        int row = flat >> 6, col = flat & 63;          // row = n-local, col = c-local
        op[(size_t)row * 256 + col] = (bf16)tile[col][row];
    }
}

// ---------------------------------------------------------------- q GEMM
// D[n][c] = sum_i xT[n][i] * Wq_bf[c][i]   (A rows = xT, B rows = Wq_bf)
__launch_bounds__(256)
__global__ void k_gemm_q(const bf16* __restrict__ xT, const bf16* __restrict__ Wq_bf,
                         bf16* __restrict__ q_t) {
    int b = blockIdx.z;
    int n0 = blockIdx.x * 64, c0 = blockIdx.y * 64;
    int t = threadIdx.x, l = t & 63, w = t >> 6;
    int wn = (w & 1) * 32, wc = (w >> 1) * 32;         // wave tile 32x32 in 64x64 block
    int lr = l & 15, lg = l >> 4;
    const bf16* Ab = xT + (size_t)(b * 4096 + n0 + wn + lr) * 256 + lg * 8;
    const bf16* Bb = Wq_bf + (size_t)(c0 + wc + lr) * 256 + lg * 8;
    f32x4 acc[2][2] = {};
#pragma unroll
    for (int kk = 0; kk < 8; kk++) {
        bf16x8 a0 = *(const bf16x8*)(Ab + kk * 32);
        bf16x8 a1 = *(const bf16x8*)(Ab + 16 * 256 + kk * 32);
        bf16x8 b0 = *(const bf16x8*)(Bb + kk * 32);
        bf16x8 b1 = *(const bf16x8*)(Bb + 16 * 256 + kk * 32);
        acc[0][0] = MFMA16(a0, b0, acc[0][0], 0, 0, 0);
        acc[0][1] = MFMA16(a0, b1, acc[0][1], 0, 0, 0);
        acc[1][0] = MFMA16(a1, b0, acc[1][0], 0, 0, 0);
        acc[1][1] = MFMA16(a1, b1, acc[1][1], 0, 0, 0);
    }
#pragma unroll
    for (int i = 0; i < 2; i++)
#pragma unroll
        for (int j = 0; j < 2; j++) {
            int cc = c0 + wc + j * 16 + lr;            // D col = lane&15
            int h = cc >> 5, d = cc & 31;
#pragma unroll
            for (int r = 0; r < 4; r++) {
                int n = n0 + wn + i * 16 + lg * 4 + r; // D row = (lane>>4)*4+r
                q_t[((size_t)(b * 8 + h) * 4096 + n) * 32 + d] = (bf16)acc[i][j][r];
            }
        }
}

// ---------------------------------------------------------------- kv conv GEMM
// P-row fragments gathered directly from xT: P[m][k], k = tap*256+i maps to
// xT[n(m,tap)][i]; a 32-wide kk chunk stays within one tap.
__device__ inline void p_row_ptrs(const bf16* __restrict__ xb, int m, int lgofs,
                                  const bf16* __restrict__ p[4]) {
    int y = m >> 5, xw = m & 31;
    int nb = y * 128 + xw * 2;                         // top-left pixel of 2x2 patch
#pragma unroll
    for (int tap = 0; tap < 4; tap++) {
        int n = nb + (tap >> 1) * 64 + (tap & 1);
        p[tap] = xb + (size_t)n * 256 + lgofs;
    }
}
__device__ inline void c_row_ptrs(const bf16* __restrict__ row, int lgofs,
                                  const bf16* __restrict__ p[4]) {
#pragma unroll
    for (int tap = 0; tap < 4; tap++) p[tap] = row + tap * 256 + lgofs;
}

// zz<4 : kpos  D[m][c]  (A rows = P(xT),  B rows = Wkv_bf[0..255])   + rel bias
// zz>=4: v     D[c][m]  (A rows = Wkv_bf[256..511], B rows = P(xT)) -> fp16
__launch_bounds__(256)
__global__ void k_gemm_kv(const bf16* __restrict__ xT, const bf16* __restrict__ Wkv_bf,
                          const float* __restrict__ rel_h, const float* __restrict__ rel_w,
                          bf16* __restrict__ kpos_t, _Float16* __restrict__ v_td) {
    int b = blockIdx.z;
    int m0 = blockIdx.x * 64;
    int zz = blockIdx.y;
    bool vmode = zz >= 4;
    int c0 = (zz & 3) * 64;
    int t = threadIdx.x, l = t & 63, w = t >> 6;
    int wr = (w & 1) * 32, wc = (w >> 1) * 32;
    int lr = l & 15, lg = l >> 4;
    int lgofs = lg * 8;
    const bf16* xb = xT + (size_t)b * 4096 * 256;
    const bf16 *A0[4], *A1[4], *B0[4], *B1[4];
    if (!vmode) {
        p_row_ptrs(xb, m0 + wr + lr, lgofs, A0);
        p_row_ptrs(xb, m0 + wr + 16 + lr, lgofs, A1);
        c_row_ptrs(Wkv_bf + (size_t)(c0 + wc + lr) * 1024, lgofs, B0);
        c_row_ptrs(Wkv_bf + (size_t)(c0 + wc + 16 + lr) * 1024, lgofs, B1);
    } else {
        c_row_ptrs(Wkv_bf + (size_t)(256 + c0 + wr + lr) * 1024, lgofs, A0);
        c_row_ptrs(Wkv_bf + (size_t)(256 + c0 + wr + 16 + lr) * 1024, lgofs, A1);
        p_row_ptrs(xb, m0 + wc + lr, lgofs, B0);
        p_row_ptrs(xb, m0 + wc + 16 + lr, lgofs, B1);
    }
    f32x4 acc[2][2] = {};
#pragma unroll
    for (int tap = 0; tap < 4; tap++) {
#pragma unroll
        for (int j = 0; j < 8; j++) {
            int o = j * 32;
            bf16x8 a0 = *(const bf16x8*)(A0[tap] + o);
            bf16x8 a1 = *(const bf16x8*)(A1[tap] + o);
            bf16x8 b0 = *(const bf16x8*)(B0[tap] + o);
            bf16x8 b1 = *(const bf16x8*)(B1[tap] + o);
            acc[0][0] = MFMA16(a0, b0, acc[0][0], 0, 0, 0);
            acc[0][1] = MFMA16(a0, b1, acc[0][1], 0, 0, 0);
            acc[1][0] = MFMA16(a1, b0, acc[1][0], 0, 0, 0);
            acc[1][1] = MFMA16(a1, b1, acc[1][1], 0, 0, 0);
        }
    }
    if (!vmode) {
#pragma unroll
        for (int i = 0; i < 2; i++)
#pragma unroll
            for (int j = 0; j < 2; j++) {
                int cc = c0 + wc + j * 16 + lr;
#pragma unroll
                for (int r = 0; r < 4; r++) {
                    int m = m0 + wr + i * 16 + lg * 4 + r;
                    // pos[h,d,m] = rel_w[h,d,y=m>>5] + rel_h[h,d,x=m&31]
                    float val = acc[i][j][r] + rel_w[cc * 32 + (m >> 5)]
                                            + rel_h[cc * 32 + (m & 31)];
                    kpos_t[((size_t)(b * 8 + (cc >> 5)) * 1024 + m) * 32 + (cc & 31)] = (bf16)val;
                }
            }
    } else {
#pragma unroll
        for (int i = 0; i < 2; i++)
#pragma unroll
            for (int j = 0; j < 2; j++) {
                int m = m0 + wc + j * 16 + lr;
#pragma unroll
                for (int r = 0; r < 4; r++) {
                    int cc = c0 + wr + i * 16 + lg * 4 + r;
                    v_td[((size_t)(b * 8 + (cc >> 5)) * 32 + (cc & 31)) * 1024 + m] = (_Float16)acc[i][j][r];
                }
            }
    }
}

// ---------------------------------------------------------------- attention
// Block = 4 waves x 32 queries = 128 q sharing K/V staged in LDS.
// 4 passes of 256 m: stage Ks[256][32] bf16 (16KB, contiguous copy) +
// Vs[32][264] f16 (16.5KB, +8 pad -> 2-way-aliased frag reads).
// S^T = K·Q^T lands P in the 16x16x16 PV A-frag layout; shift via C operand.
__launch_bounds__(256)
__global__ void k_attn(const bf16* __restrict__ q_t, const bf16* __restrict__ kpos_t,
                       const _Float16* __restrict__ v_td, float* __restrict__ out) {
    int b = blockIdx.z, h = blockIdx.y;
    int t = threadIdx.x;
    int w = t >> 6, l = t & 63;
    int n0 = blockIdx.x * 128 + w * 32;
    int lr = l & 15, lg = l >> 4;
    const size_t bh = (size_t)(b * 8 + h);
    __shared__ __align__(16) bf16 Ks[256 * 32];        // [m_local][d], 64B rows
    __shared__ __align__(16) _Float16 Vs[32][264];     // [d][m_local], pad +8
    // Q as B-operand: B row j = n = lr, k = d = lg*8..+8
    bf16x8 bq0 = *(const bf16x8*)(q_t + (bh * 4096 + n0 + lr) * 32 + lg * 8);
    bf16x8 bq1 = *(const bf16x8*)(q_t + (bh * 4096 + n0 + 16 + lr) * 32 + lg * 8);
    const bf16* Kb = kpos_t + bh * 1024 * 32;
    const _Float16* Vb = v_td + bh * 32 * 1024;
    f32x4 accO[2][2] = {};          // [n-half][d-tile]: col d = lr, row n = lg*4+r
    float ps0 = 0.f, ps1 = 0.f;     // per-lane row-sum partials (n = lr)
    const f32x4 zs = {-SOFTMAX_SHIFT, -SOFTMAX_SHIFT, -SOFTMAX_SHIFT, -SOFTMAX_SHIFT};
    for (int pass = 0; pass < 4; pass++) {
        // --- stage K chunk: rows [pass*256, +256) are 16KB contiguous
        const uint4* ksrc = (const uint4*)(Kb + (size_t)pass * 256 * 32);
        uint4* kdst = (uint4*)Ks;
#pragma unroll
        for (int j = 0; j < 4; j++) kdst[t + j * 256] = ksrc[t + j * 256];
        // --- stage V chunk: 32 rows x 512B segments -> padded LDS rows
#pragma unroll
        for (int j = 0; j < 4; j++) {
            int u = t + j * 256;                       // 0..1023 16B-units
            int row = u >> 5, col = u & 31;
            *(uint4*)(&Vs[row][col * 8]) =
                *(const uint4*)(Vb + (size_t)row * 1024 + pass * 256 + col * 8);
        }
        __syncthreads();
#pragma unroll 4
        for (int tt = 0; tt < 16; tt++) {
            // K as A-operand: A row i = m_local = tt*16+lr, k = d
            bf16x8 ak = *(const bf16x8*)(Ks + (tt * 16 + lr) * 32 + lg * 8);
            f32x4 s0 = MFMA16(ak, bq0, zs, 0, 0, 0);   // col n=lr, row m=tt*16+lg*4+r
            f32x4 s1 = MFMA16(ak, bq1, zs, 0, 0, 0);
            f16x4 p0, p1;
#pragma unroll
            for (int r = 0; r < 4; r++) {
                float e0 = fminf(__builtin_amdgcn_exp2f(s0[r]), 65504.f);
                float e1 = fminf(__builtin_amdgcn_exp2f(s1[r]), 65504.f);
                ps0 += e0; ps1 += e1;
                p0[r] = (_Float16)e0; p1[r] = (_Float16)e1;
            }
            // V as B-operand (k=16): B row j = d = lr, k = m_local = tt*16+lg*4+jj
            f16x4 v0 = *(const f16x4*)(&Vs[lr][tt * 16 + lg * 4]);
            f16x4 v1 = *(const f16x4*)(&Vs[16 + lr][tt * 16 + lg * 4]);
            accO[0][0] = MFMA16H(p0, v0, accO[0][0], 0, 0, 0);
            accO[0][1] = MFMA16H(p0, v1, accO[0][1], 0, 0, 0);
            accO[1][0] = MFMA16H(p1, v0, accO[1][0], 0, 0, 0);
            accO[1][1] = MFMA16H(p1, v1, accO[1][1], 0, 0, 0);
        }
        __syncthreads();
    }
    // row sums: lanes {lr, lr+16, lr+32, lr+48} hold disjoint m-partials
    ps0 += __shfl_xor(ps0, 16, 64); ps0 += __shfl_xor(ps0, 32, 64);
    ps1 += __shfl_xor(ps1, 16, 64); ps1 += __shfl_xor(ps1, 32, 64);
    float inv0[4], inv1[4];
#pragma unroll
    for (int r = 0; r < 4; r++) {
        inv0[r] = 1.0f / __shfl(ps0, lg * 4 + r, 64);
        inv1[r] = 1.0f / __shfl(ps1, lg * 4 + r, 64);
    }
#pragma unroll
    for (int dt = 0; dt < 2; dt++) {
        int c = h * 32 + dt * 16 + lr;     // accO col = d = lr
        float* op0 = out + (size_t)(b * 256 + c) * 4096 + n0 + lg * 4;
        float* op1 = op0 + 16;
        f32x4 o0, o1;
#pragma unroll
        for (int r = 0; r < 4; r++) {
            o0[r] = accO[0][dt][r] * inv0[r];
            o1[r] = accO[1][dt][r] * inv1[r];
        }
        *(f32x4*)op0 = o0;
        *(f32x4*)op1 = o1;
    }
}

// ---------------------------------------------------------------- launcher
extern "C" void kernel_launch(void* const* d_in, const int* in_sizes, int n_in,
                              void* d_out, int out_size, void* d_ws, size_t ws_size,
                              hipStream_t stream) {
    const float* x    = (const float*)d_in[0];
    const float* Wq   = (const float*)d_in[1];
    const float* Wk   = (const float*)d_in[2];
    const float* Wv   = (const float*)d_in[3];
    const float* relh = (const float*)d_in[4];
    const float* relw = (const float*)d_in[5];
    float* out = (float*)d_out;
    char* ws = (char*)d_ws;

    bf16*      xT     = (bf16*)(ws);                                  // 8 MiB
    bf16*      q_t    = (bf16*)(ws + (8u << 20));                     // 8 MiB
    bf16*      kposT  = (bf16*)(ws + (16u << 20));                    // 2 MiB
    _Float16*  v_td   = (_Float16*)(ws + (18u << 20));                // 2 MiB
    bf16*      Wq_bf  = (bf16*)(ws + (20u << 20));                    // 128 KiB
    bf16*      Wkv_bf = (bf16*)(ws + (20u << 20) + (256u << 10));     // 1 MiB

    k_prep_w <<<256,            256, 0, stream>>>(Wq, Wk, Wv, Wq_bf, Wkv_bf);
    k_xT     <<<dim3(64, 4, 4), 256, 0, stream>>>(x, xT);
    k_gemm_q <<<dim3(64, 4, 4), 256, 0, stream>>>(xT, Wq_bf, q_t);
    k_gemm_kv<<<dim3(16, 8, 4), 256, 0, stream>>>(xT, Wkv_bf, relh, relw, kposT, v_td);
    k_attn   <<<dim3(32, 8, 4), 256, 0, stream>>>(q_t, kposT, v_td, out);
}